// Round 5
// baseline (212.591 us; speedup 1.0000x reference)
//
#include <hip/hip_runtime.h>

#define IN_CH 96
#define OUT_CH 384
#define THREADS 384

typedef float f32x4 __attribute__((ext_vector_type(4)));

// Barrier-free + software-pipelined:
//   iter i: issue loads(q_{i+1})  [BEFORE the store -> loads stay oldest in
//           the vmcnt FIFO]; compute(q_i); store(q_i).
// This lets the compute wait be a counted vmcnt that tolerates one
// outstanding store + the next prefetch, instead of serializing on the
// previous store's ack every iteration. Stores are plain (not nontemporal)
// so the ack comes from L2 acceptance, not HBM.
//
// Thread t: channel-group cg = t%96 (4 consecutive output channels of joint
// cg>>2), row lane rl = t/96 (row 4q+rl). 12-float contiguous x-window
// (3x dwordx4, 3x overlap served by L1), 48 FMAs, one float4 store.
__global__ __launch_bounds__(THREADS, 5) void skel_linear_kernel(
    const float* __restrict__ x,
    const float* __restrict__ weight,
    const float* __restrict__ mask,
    const float* __restrict__ bias,
    float* __restrict__ out,
    int batch)
{
    const int t     = threadIdx.x;
    const int cg    = t % 96;
    const int rl    = t / 96;          // 0..3
    const int chan  = cg * 4;
    const int joint = cg >> 2;
    const int jc    = (joint - 1 < 0) ? 0 : ((joint - 1 > 21) ? 21 : joint - 1);
    const int c0    = jc * 4;          // contiguous 12-col window [c0, c0+12)

    // Hoist masked weights + bias into registers (once per launch).
    float w[4][12];
    float b[4];
#pragma unroll
    for (int j = 0; j < 4; ++j) {
        const size_t row = (size_t)(chan + j) * IN_CH;
#pragma unroll
        for (int c = 0; c < 12; ++c)
            w[j][c] = weight[row + c0 + c] * mask[row + c0 + c];
        b[j] = bias[chan + j];
    }

    const int nquads = batch >> 2;              // 65536
    const int stride = gridDim.x;
    // Uniform trip count per block, last iteration peeled (no branch in body).
    const int niter  = (nquads - blockIdx.x + stride - 1) / stride;

    // Incremental pointers (floats): x offset = q*384 + rl*96 + c0,
    // out offset = q*1536 + rl*384 + chan.
    const float* xp = x   + (size_t)blockIdx.x * (4 * IN_CH)  + rl * IN_CH  + c0;
    float*       op = out + (size_t)blockIdx.x * (4 * OUT_CH) + rl * OUT_CH + chan;
    const size_t xstep = (size_t)stride * (4 * IN_CH);
    const size_t ostep = (size_t)stride * (4 * OUT_CH);

    // Prologue: load first quad.
    f32x4 xa = *reinterpret_cast<const f32x4*>(xp);
    f32x4 xb = *reinterpret_cast<const f32x4*>(xp + 4);
    f32x4 xc = *reinterpret_cast<const f32x4*>(xp + 8);
    xp += xstep;

    for (int i = 0; i < niter - 1; ++i) {
        // Prefetch next quad BEFORE this iteration's store.
        const f32x4 na = *reinterpret_cast<const f32x4*>(xp);
        const f32x4 nb = *reinterpret_cast<const f32x4*>(xp + 4);
        const f32x4 nc = *reinterpret_cast<const f32x4*>(xp + 8);
        xp += xstep;

        f32x4 o4;
#pragma unroll
        for (int j = 0; j < 4; ++j) {
            float acc = b[j];
            acc = fmaf(w[j][0],  xa.x, acc);
            acc = fmaf(w[j][1],  xa.y, acc);
            acc = fmaf(w[j][2],  xa.z, acc);
            acc = fmaf(w[j][3],  xa.w, acc);
            acc = fmaf(w[j][4],  xb.x, acc);
            acc = fmaf(w[j][5],  xb.y, acc);
            acc = fmaf(w[j][6],  xb.z, acc);
            acc = fmaf(w[j][7],  xb.w, acc);
            acc = fmaf(w[j][8],  xc.x, acc);
            acc = fmaf(w[j][9],  xc.y, acc);
            acc = fmaf(w[j][10], xc.z, acc);
            acc = fmaf(w[j][11], xc.w, acc);
            o4[j] = acc;
        }
        *reinterpret_cast<f32x4*>(op) = o4;
        op += ostep;

        xa = na; xb = nb; xc = nc;
    }

    // Epilogue: last quad (no prefetch).
    {
        f32x4 o4;
#pragma unroll
        for (int j = 0; j < 4; ++j) {
            float acc = b[j];
            acc = fmaf(w[j][0],  xa.x, acc);
            acc = fmaf(w[j][1],  xa.y, acc);
            acc = fmaf(w[j][2],  xa.z, acc);
            acc = fmaf(w[j][3],  xa.w, acc);
            acc = fmaf(w[j][4],  xb.x, acc);
            acc = fmaf(w[j][5],  xb.y, acc);
            acc = fmaf(w[j][6],  xb.z, acc);
            acc = fmaf(w[j][7],  xb.w, acc);
            acc = fmaf(w[j][8],  xc.x, acc);
            acc = fmaf(w[j][9],  xc.y, acc);
            acc = fmaf(w[j][10], xc.z, acc);
            acc = fmaf(w[j][11], xc.w, acc);
            o4[j] = acc;
        }
        *reinterpret_cast<f32x4*>(op) = o4;
    }
}

extern "C" void kernel_launch(void* const* d_in, const int* in_sizes, int n_in,
                              void* d_out, int out_size, void* d_ws, size_t ws_size,
                              hipStream_t stream) {
    const float* x      = (const float*)d_in[0];
    const float* weight = (const float*)d_in[1];
    const float* mask   = (const float*)d_in[2];
    const float* bias   = (const float*)d_in[3];
    float* out          = (float*)d_out;

    const int batch = in_sizes[0] / IN_CH;   // 262144
    const int grid  = 768;   // 256 CUs x 3 resident blocks (6 waves, ~88 VGPR)

    skel_linear_kernel<<<grid, THREADS, 0, stream>>>(x, weight, mask, bias, out, batch);
}